// Round 2
// baseline (1005.805 us; speedup 1.0000x reference)
//
#include <hip/hip_runtime.h>
#include <stdint.h>

// ---------------------------------------------------------------------------
// MoE FFN with Sinkhorn (OT) routing.  Shapes: N=4096 tokens, D=1024, F=4096,
// E=8 experts, top-2.  Pipeline:
//   K1: la[n][e] = -logits/eps (fp32)
//   K2: single-block Sinkhorn, 20 iters (iter-1 row pass in log domain, rest
//       linear) -> slot weights pi[:,0/1], top-2 ids, expert lists, tile descs
//   K3: grouped GEMM  H = silu(X Wg^T) * (X Wu^T) * w_slot   (bf16 MFMA)
//   K4: grouped GEMM  out += H Wd^T  (atomicAdd combine)
// ---------------------------------------------------------------------------

typedef short short8 __attribute__((ext_vector_type(8)));
typedef float f32x4 __attribute__((ext_vector_type(4)));

#define NTOK 4096
#define DD   1024
#define FF   4096
#define NE   8
#define EPSI 0.05f
#define NITER 20

// ws byte offsets
#define WS_LA      0            // 4096*8*4
#define WS_WK      131072       // 4096*2*4
#define WS_CNT     163840       // 8*4
#define WS_OFF     163872       // 8*4
#define WS_NT64    163904
#define WS_NT128   163908
#define WS_DESC64  164096       // up to 160 ints
#define WS_DESC128 164736       // up to 72 ints
#define WS_LISTS   165376       // 8*4096*4
#define WS_H       (1u<<20)     // 8192*4096*2 bytes bf16

#define BM3 64
#define BF3 128
#define BK3 32
#define BM4 128
#define BD4 128
#define BK4 32
#define PITCH 40                // LDS row pitch in bf16 elems (80B => uniform 2-way banks, free)

__device__ inline unsigned int bfr(float f) {        // fp32 -> bf16 bits, RNE
  unsigned int u = __builtin_bit_cast(unsigned int, f);
  return (u + 0x7fffu + ((u >> 16) & 1u)) >> 16;
}
__device__ inline uint2 pack4(float4 v) {
  return make_uint2(bfr(v.x) | (bfr(v.y) << 16), bfr(v.z) | (bfr(v.w) << 16));
}

// ---------------- K1: gating logits -> la = -logits/eps ----------------
__global__ void k_logits(const float* __restrict__ x, const float* __restrict__ gw,
                         float* __restrict__ la) {
  int wid = threadIdx.x >> 6, lane = threadIdx.x & 63;
  int n = blockIdx.x * 4 + wid;
  const float4* x4 = reinterpret_cast<const float4*>(x) + (size_t)n * (DD / 4);
  const float4* g4 = reinterpret_cast<const float4*>(gw);
  float acc[NE];
#pragma unroll
  for (int e = 0; e < NE; e++) acc[e] = 0.f;
#pragma unroll
  for (int j = 0; j < 4; j++) {
    float4 xv = x4[j * 64 + lane];
#pragma unroll
    for (int e = 0; e < NE; e++) {
      float4 gv = g4[e * (DD / 4) + j * 64 + lane];
      acc[e] += xv.x * gv.x + xv.y * gv.y + xv.z * gv.z + xv.w * gv.w;
    }
  }
#pragma unroll
  for (int off = 32; off; off >>= 1)
#pragma unroll
    for (int e = 0; e < NE; e++) acc[e] += __shfl_xor(acc[e], off);
  if (lane < NE) la[n * NE + lane] = acc[lane] * (-1.0f / EPSI);
}

// ---------------- K2: Sinkhorn (linear domain after iter-1 row pass) --------
__global__ void __launch_bounds__(1024) k_sinkhorn(
    const float* __restrict__ ws_la, float* __restrict__ wk,
    int* __restrict__ cnt_g, int* __restrict__ off_g,
    int* __restrict__ nt64, int* __restrict__ nt128,
    int* __restrict__ desc64, int* __restrict__ desc128,
    int* __restrict__ lists) {
  int tid = threadIdx.x;
  __shared__ float red[16][NE];          // per-wave colsum partials
  __shared__ float colR[NE];             // 1/colsum broadcast
  __shared__ int cntS[NE];
  if (tid < NE) cntS[tid] = 0;

  float P[4][NE];
  int n0 = tid * 4;
  int lane = tid & 63, wid = tid >> 6;

  // ---- iteration 1 row pass in log domain (inputs range +-60) ----
#pragma unroll
  for (int r = 0; r < 4; r++) {
    float v[NE];
#pragma unroll
    for (int e = 0; e < NE; e++) v[e] = ws_la[(n0 + r) * NE + e];
    float m = v[0];
#pragma unroll
    for (int e = 1; e < NE; e++) m = fmaxf(m, v[e]);
    float s = 0.f;
#pragma unroll
    for (int e = 0; e < NE; e++) { v[e] = __expf(v[e] - m); s += v[e]; }
    float ri = 1.0f / s;
#pragma unroll
    for (int e = 0; e < NE; e++) P[r][e] = v[e] * ri;   // row-stochastic
  }

  // ---- 20 column passes + 19 linear row passes, interleaved ----
  for (int it = 0; it < NITER; ++it) {
    if (it) {            // linear row normalization (rows sum over 8 experts)
#pragma unroll
      for (int r = 0; r < 4; r++) {
        float s = 0.f;
#pragma unroll
        for (int e = 0; e < NE; e++) s += P[r][e];
        float ri = 1.0f / s;
#pragma unroll
        for (int e = 0; e < NE; e++) P[r][e] *= ri;
      }
    }
    // column sums across 4096 rows
    float cs[NE];
#pragma unroll
    for (int e = 0; e < NE; e++)
      cs[e] = P[0][e] + P[1][e] + P[2][e] + P[3][e];
#pragma unroll
    for (int off = 32; off; off >>= 1)
#pragma unroll
      for (int e = 0; e < NE; e++) cs[e] += __shfl_xor(cs[e], off);
    if (lane == 0)
#pragma unroll
      for (int e = 0; e < NE; e++) red[wid][e] = cs[e];
    __syncthreads();
    if (tid < NE) {
      float S = red[0][tid];
      for (int w = 1; w < 16; w++) S += red[w][tid];
      colR[tid] = 1.0f / S;
    }
    __syncthreads();
#pragma unroll
    for (int r = 0; r < 4; r++)
#pragma unroll
      for (int e = 0; e < NE; e++) P[r][e] *= colR[e];
    __syncthreads();
  }

  // ---- per-row outputs: slot weights pi[:,0/1]; top-2 experts (low-idx ties)
  for (int r = 0; r < 4; r++) {
    int n = n0 + r;
    wk[n * 2 + 0] = P[r][0];
    wk[n * 2 + 1] = P[r][1];
    int e0 = 0; float b = P[r][0];
    for (int e = 1; e < NE; e++) if (P[r][e] > b) { b = P[r][e]; e0 = e; }
    int e1 = -1; float b2 = -1e30f;
    for (int e = 0; e < NE; e++) if (e != e0 && P[r][e] > b2) { b2 = P[r][e]; e1 = e; }
    int p = atomicAdd(&cntS[e0], 1); lists[e0 * NTOK + p] = n * 2;
    p     = atomicAdd(&cntS[e1], 1); lists[e1 * NTOK + p] = n * 2 + 1;
  }
  __syncthreads();
  if (tid == 0) {
    int run = 0, i64 = 0, i128 = 0;
    for (int e = 0; e < NE; e++) {
      int c = cntS[e];
      cnt_g[e] = c; off_g[e] = run;
      for (int t = 0; t < (c + BM3 - 1) / BM3; t++)  desc64[i64++]   = (e << 16) | t;
      for (int t = 0; t < (c + BM4 - 1) / BM4; t++)  desc128[i128++] = (e << 16) | t;
      run += c;
    }
    *nt64 = i64; *nt128 = i128;
  }
}

// ---------------- K3: H = silu(X Wg^T) * (X Wu^T) * w_slot ----------------
__global__ void __launch_bounds__(256) k_ffn1(
    const float* __restrict__ x, const float* __restrict__ Wg,
    const float* __restrict__ Wu, const float* __restrict__ wk,
    const int* __restrict__ cnt, const int* __restrict__ offs,
    const int* __restrict__ nt64, const int* __restrict__ desc64,
    const int* __restrict__ lists, unsigned short* __restrict__ H) {
  if ((int)blockIdx.x >= *nt64) return;
  int dsc = desc64[blockIdx.x];
  int e = dsc >> 16, t = dsc & 0xffff;
  int c = cnt[e];
  int base = offs[e] + t * BM3;
  int nrows = min(BM3, c - t * BM3);
  int f0 = blockIdx.y * BF3;

  __shared__ unsigned short A[BM3 * PITCH];
  __shared__ unsigned short Bg[BF3 * PITCH];
  __shared__ unsigned short Bu[BF3 * PITCH];
  __shared__ unsigned short Hb[BM3 * 136];
  __shared__ int tok[BM3];
  __shared__ float wrow[BM3];

  int tid = threadIdx.x;
  if (tid < BM3) {
    int token = 0; float w = 0.f;
    if (tid < nrows) {
      int entry = lists[e * NTOK + t * BM3 + tid];
      token = entry >> 1;
      w = wk[entry];                       // entry == token*2 + k
    }
    tok[tid] = token; wrow[tid] = w;
  }

  int lane = tid & 63, wid = tid >> 6;
  int wm = wid >> 1, wf = wid & 1;
  f32x4 zero = {0.f, 0.f, 0.f, 0.f};
  f32x4 accG[2][4], accU[2][4];
#pragma unroll
  for (int i = 0; i < 2; i++)
#pragma unroll
    for (int j = 0; j < 4; j++) { accG[i][j] = zero; accU[i][j] = zero; }

  const float* wgB = Wg + (size_t)e * FF * DD + (size_t)f0 * DD;
  const float* wuB = Wu + (size_t)e * FF * DD + (size_t)f0 * DD;
  int srow = tid >> 3;                 // 0..31
  int sk = (tid & 7) * 4;              // float offset in BK

  for (int k0 = 0; k0 < DD; k0 += BK3) {
    __syncthreads();
#pragma unroll
    for (int p = 0; p < 2; p++) {      // A: 64 rows (gathered tokens)
      int r = p * 32 + srow;
      float4 v = *reinterpret_cast<const float4*>(x + (size_t)tok[r] * DD + k0 + sk);
      *reinterpret_cast<uint2*>(&A[r * PITCH + sk]) = pack4(v);
    }
#pragma unroll
    for (int p = 0; p < 4; p++) {      // Bg/Bu: 128 rows of (F,D) weights
      int r = p * 32 + srow;
      float4 v = *reinterpret_cast<const float4*>(wgB + (size_t)r * DD + k0 + sk);
      *reinterpret_cast<uint2*>(&Bg[r * PITCH + sk]) = pack4(v);
      float4 v2 = *reinterpret_cast<const float4*>(wuB + (size_t)r * DD + k0 + sk);
      *reinterpret_cast<uint2*>(&Bu[r * PITCH + sk]) = pack4(v2);
    }
    __syncthreads();
    int arow = lane & 15, kb = (lane >> 4) * 8;
    short8 af[2];
#pragma unroll
    for (int fm = 0; fm < 2; fm++)
      af[fm] = *reinterpret_cast<const short8*>(&A[(wm * 32 + fm * 16 + arow) * PITCH + kb]);
#pragma unroll
    for (int ff = 0; ff < 4; ff++) {
      short8 bg = *reinterpret_cast<const short8*>(&Bg[(wf * 64 + ff * 16 + arow) * PITCH + kb]);
      short8 bu = *reinterpret_cast<const short8*>(&Bu[(wf * 64 + ff * 16 + arow) * PITCH + kb]);
#pragma unroll
      for (int fm = 0; fm < 2; fm++) {
        accG[fm][ff] = __builtin_amdgcn_mfma_f32_16x16x32_bf16(af[fm], bg, accG[fm][ff], 0, 0, 0);
        accU[fm][ff] = __builtin_amdgcn_mfma_f32_16x16x32_bf16(af[fm], bu, accU[fm][ff], 0, 0, 0);
      }
    }
  }
  // epilogue: silu(g)*u*w  -> LDS bounce -> coalesced global
#pragma unroll
  for (int fm = 0; fm < 2; fm++)
#pragma unroll
    for (int ff = 0; ff < 4; ff++)
#pragma unroll
      for (int j = 0; j < 4; j++) {
        int rl = wm * 32 + fm * 16 + (lane >> 4) * 4 + j;
        int cl = wf * 64 + ff * 16 + (lane & 15);
        float g = accG[fm][ff][j], u = accU[fm][ff][j];
        float h = g / (1.f + __expf(-g)) * u * wrow[rl];
        Hb[rl * 136 + cl] = (unsigned short)bfr(h);
      }
  __syncthreads();
  int r = tid >> 2, sg = tid & 3;
  if (r < nrows) {
    unsigned short* dst = H + (size_t)(base + r) * FF + f0 + sg * 32;
    const unsigned short* src = &Hb[r * 136 + sg * 32];
#pragma unroll
    for (int j = 0; j < 4; j++)
      *reinterpret_cast<uint4*>(dst + j * 8) = *reinterpret_cast<const uint4*>(src + j * 8);
  }
}

// ---------------- K4: out += H Wd^T (weights already folded into H) ----------------
__global__ void __launch_bounds__(256) k_ffn2(
    const unsigned short* __restrict__ H, const float* __restrict__ Wd,
    const int* __restrict__ cnt, const int* __restrict__ offs,
    const int* __restrict__ nt128, const int* __restrict__ desc128,
    const int* __restrict__ lists, float* __restrict__ out) {
  if ((int)blockIdx.x >= *nt128) return;
  int dsc = desc128[blockIdx.x];
  int e = dsc >> 16, t = dsc & 0xffff;
  int c = cnt[e];
  int base = offs[e] + t * BM4;
  int nrows = min(BM4, c - t * BM4);
  int d0 = blockIdx.y * BD4;

  __shared__ unsigned short A[BM4 * PITCH];
  __shared__ unsigned short B[BD4 * PITCH];
  __shared__ int tok[BM4];

  int tid = threadIdx.x;
  if (tid < BM4) {
    int token = 0;
    if (tid < nrows) token = lists[e * NTOK + t * BM4 + tid] >> 1;
    tok[tid] = token;
  }

  int lane = tid & 63, wid = tid >> 6;
  int wm = wid >> 1, wd = wid & 1;
  f32x4 zero = {0.f, 0.f, 0.f, 0.f};
  f32x4 acc[4][4];
#pragma unroll
  for (int i = 0; i < 4; i++)
#pragma unroll
    for (int j = 0; j < 4; j++) acc[i][j] = zero;

  const float* wdB = Wd + (size_t)e * DD * FF + (size_t)d0 * FF;

  for (int k0 = 0; k0 < FF; k0 += BK4) {
    __syncthreads();
#pragma unroll
    for (int p = 0; p < 2; p++) {      // A: 128 rows of bf16 H (contiguous slots)
      int r = p * 64 + (tid >> 2);
      int slot = min(base + r, NTOK * 2 - 1);
      const unsigned short* src = H + (size_t)slot * FF + k0 + (tid & 3) * 8;
      *reinterpret_cast<uint4*>(&A[r * PITCH + (tid & 3) * 8]) =
          *reinterpret_cast<const uint4*>(src);
    }
#pragma unroll
    for (int p = 0; p < 4; p++) {      // B: 128 rows (d) of Wd (D,F) fp32
      int r = p * 32 + (tid >> 3);
      float4 v = *reinterpret_cast<const float4*>(wdB + (size_t)r * FF + k0 + (tid & 7) * 4);
      *reinterpret_cast<uint2*>(&B[r * PITCH + (tid & 7) * 4]) = pack4(v);
    }
    __syncthreads();
    int arow = lane & 15, kb = (lane >> 4) * 8;
    short8 af[4], bf[4];
#pragma unroll
    for (int i = 0; i < 4; i++)
      af[i] = *reinterpret_cast<const short8*>(&A[(wm * 64 + i * 16 + arow) * PITCH + kb]);
#pragma unroll
    for (int i = 0; i < 4; i++)
      bf[i] = *reinterpret_cast<const short8*>(&B[(wd * 64 + i * 16 + arow) * PITCH + kb]);
#pragma unroll
    for (int i = 0; i < 4; i++)
#pragma unroll
      for (int j = 0; j < 4; j++)
        acc[i][j] = __builtin_amdgcn_mfma_f32_16x16x32_bf16(af[i], bf[j], acc[i][j], 0, 0, 0);
  }
#pragma unroll
  for (int i = 0; i < 4; i++)
#pragma unroll
    for (int j = 0; j < 4; j++)
#pragma unroll
      for (int q = 0; q < 4; q++) {
        int rl = wm * 64 + i * 16 + (lane >> 4) * 4 + q;
        if (rl < nrows) {
          int cl = wd * 64 + j * 16 + (lane & 15);
          atomicAdd(&out[(size_t)tok[rl] * DD + d0 + cl], acc[i][j][q]);
        }
      }
}

extern "C" void kernel_launch(void* const* d_in, const int* in_sizes, int n_in,
                              void* d_out, int out_size, void* d_ws, size_t ws_size,
                              hipStream_t stream) {
  (void)in_sizes; (void)n_in; (void)ws_size;
  const float* x  = (const float*)d_in[0];
  const float* gw = (const float*)d_in[1];
  const float* Wg = (const float*)d_in[2];
  const float* Wu = (const float*)d_in[3];
  const float* Wd = (const float*)d_in[4];
  float* out = (float*)d_out;
  char* ws = (char*)d_ws;

  float* la   = (float*)(ws + WS_LA);
  float* wk   = (float*)(ws + WS_WK);
  int* cnt    = (int*)(ws + WS_CNT);
  int* offs   = (int*)(ws + WS_OFF);
  int* nt64   = (int*)(ws + WS_NT64);
  int* nt128  = (int*)(ws + WS_NT128);
  int* d64    = (int*)(ws + WS_DESC64);
  int* d128   = (int*)(ws + WS_DESC128);
  int* lists  = (int*)(ws + WS_LISTS);
  unsigned short* H = (unsigned short*)(ws + WS_H);

  hipMemsetAsync(d_out, 0, (size_t)out_size * sizeof(float), stream);
  k_logits<<<NTOK / 4, 256, 0, stream>>>(x, gw, la);
  k_sinkhorn<<<1, 1024, 0, stream>>>(la, wk, cnt, offs, nt64, nt128, d64, d128, lists);
  k_ffn1<<<dim3(136, FF / BF3), 256, 0, stream>>>(x, Wg, Wu, wk, cnt, offs, nt64, d64, lists, H);
  k_ffn2<<<dim3(72, DD / BD4), 256, 0, stream>>>(H, Wd, cnt, offs, nt128, d128, lists, out);
}